// Round 11
// baseline (35.823 us; speedup 1.0000x reference)
//
#include <hip/hip_runtime.h>
#include <math.h>

#define NQ 12
#define NLAYERS 5
#define TPB 256

typedef float v4f __attribute__((ext_vector_type(4)));
typedef short v8s __attribute__((ext_vector_type(8)));

#define MFMA(A, B, C) __builtin_amdgcn_mfma_f32_16x16x32_bf16((A), (B), (C), 0, 0, 0)

// ---- complex helpers (gate/W build) ----
__device__ __forceinline__ float2 cmulf(float2 a, float2 b) {
    return make_float2(a.x * b.x - a.y * b.y, a.x * b.y + a.y * b.x);
}
__device__ __forceinline__ float2 caddf(float2 a, float2 b) {
    return make_float2(a.x + b.x, a.y + b.y);
}
__device__ __forceinline__ void mat2mul(const float2 A[4], const float2 B[4], float2 C[4]) {
    C[0] = caddf(cmulf(A[0], B[0]), cmulf(A[1], B[2]));
    C[1] = caddf(cmulf(A[0], B[1]), cmulf(A[1], B[3]));
    C[2] = caddf(cmulf(A[2], B[0]), cmulf(A[3], B[2]));
    C[3] = caddf(cmulf(A[2], B[1]), cmulf(A[3], B[3]));
}

__device__ __forceinline__ v8s pk4(unsigned a, unsigned b, unsigned c, unsigned d) {
    union { unsigned u[4]; v8s s; } x;
    x.u[0] = a; x.u[1] = b; x.u[2] = c; x.u[3] = d;
    return x.s;
}
__device__ __forceinline__ unsigned cvt2(float a, float b) {   // {bf16(a) lo16, bf16(b) hi16}
    unsigned d;
    asm("v_cvt_pk_bf16_f32 %0, %1, %2" : "=v"(d) : "v"(a), "v"(b));
    return d;
}
// f32 -> {bf16rne(f) lo16, bf16(f - hi) hi16}  (split-W: hi+lo ~ 18-bit exact)
__device__ __forceinline__ unsigned packhl_rne(float f) {
    unsigned h = cvt2(f, 0.0f);
    float lo = f - __uint_as_float(h << 16);
    unsigned l = cvt2(lo, 0.0f);
    return h | (l << 16);
}

// ---- ring-of-CNOT permutation p = y^{-1} (HW-verified R8/R9) ----
__device__ __forceinline__ int sx4(int x) { x ^= x >> 1; x ^= x >> 2; return x & 15; }
__device__ __forceinline__ int permR(int row) {
    int s = sx4(row), par = s & 1;
    return ((s ^ (par << 3)) << 8) | (par ? 0xFF : 0);
}
__device__ __forceinline__ int permT(int t) {
    int s = sx4(t), par = s & 1;
    return (par << 11) | (s << 4) | (par ? 0xF : 0);
}
__device__ __forceinline__ int permL(int lo) {
    int s = sx4(lo), par = s & 1;
    return s | (par << 11);
}

// ---- GF(2)-linear slot keying (HW-verified R9) ----
__device__ __forceinline__ int slotOf(int k) {
    int v = k >> 4, m = k & 15;
    int vk = v ^ (((v >> 3) ^ (v >> 7)) & 1);
    return (vk << 4) | ((((m >> 2) ^ v) & 3) << 2) | (m & 3);
}

// W = Kron of 4 gates (qubits 11-beta-0..3); thread -> entry (r=tid>>4, c=tid&15)
__device__ __forceinline__ void buildW(const float2* gm, int layer, int beta, int tid,
                                       unsigned& wrd, unsigned& wid) {
    const int r = tid >> 4, c = tid & 15;
    float2 u = make_float2(1.f, 0.f);
    #pragma unroll
    for (int bb = 0; bb < 4; ++bb) {
        const float2 e = gm[(layer * 12 + 11 - beta - bb) * 4 + ((r >> bb) & 1) * 2 + ((c >> bb) & 1)];
        u = cmulf(u, e);
    }
    wrd = packhl_rne(u.x);
    wid = packhl_rne(u.y);
}

// Build the 4 split-bf16 A-fragments {Wr,-Wi}h/l, {Wi,Wr}h/l from W planes.
__device__ __forceinline__ void makeAfrags(const unsigned* wrR, const unsigned* wiR, int af,
                                           v8s& a_crh, v8s& a_crl, v8s& a_cih, v8s& a_cil) {
    const uint4 wr4 = *reinterpret_cast<const uint4*>(wrR + af);
    const uint4 wi4 = *reinterpret_cast<const uint4*>(wiR + af);
    const unsigned NX = 0x80008000u;
    const unsigned SLO = 0x05040100u, SHI = 0x07060302u;
    unsigned n0 = wi4.x ^ NX, n1 = wi4.y ^ NX, n2 = wi4.z ^ NX, n3 = wi4.w ^ NX;
    a_crh = pk4(__builtin_amdgcn_perm(n0, wr4.x, SLO), __builtin_amdgcn_perm(n1, wr4.y, SLO),
                __builtin_amdgcn_perm(n2, wr4.z, SLO), __builtin_amdgcn_perm(n3, wr4.w, SLO));
    a_crl = pk4(__builtin_amdgcn_perm(n0, wr4.x, SHI), __builtin_amdgcn_perm(n1, wr4.y, SHI),
                __builtin_amdgcn_perm(n2, wr4.z, SHI), __builtin_amdgcn_perm(n3, wr4.w, SHI));
    a_cih = pk4(__builtin_amdgcn_perm(wr4.x, wi4.x, SLO), __builtin_amdgcn_perm(wr4.y, wi4.y, SLO),
                __builtin_amdgcn_perm(wr4.z, wi4.z, SLO), __builtin_amdgcn_perm(wr4.w, wi4.w, SLO));
    a_cil = pk4(__builtin_amdgcn_perm(wr4.x, wi4.x, SHI), __builtin_amdgcn_perm(wr4.y, wi4.y, SHI),
                __builtin_amdgcn_perm(wr4.z, wi4.z, SHI), __builtin_amdgcn_perm(wr4.w, wi4.w, SHI));
}

__global__ __launch_bounds__(TPB) void qsim_kernel(const float* __restrict__ x,
                                                   const float* __restrict__ wgt,
                                                   float* __restrict__ out) {
    // Double-buffered: phase p reads buf[p&1], writes buf[(p+1)&1].
    // The p-1 barrier guarantees all waves finished READING buf[(p+1)&1]
    // (they read it in phase p-1, before that barrier) -> one barrier/phase.
    __shared__ __align__(16) unsigned st[2][4096];   // 32 KB state dbuf
    __shared__ __align__(16) unsigned wrp[2][256];   // 2 KB W-real dbuf
    __shared__ __align__(16) unsigned wip[2][256];   // 2 KB W-imag dbuf
    __shared__ __align__(16) float2 gmat[288];       // fused 2x2 gates (f32)
    __shared__ float red[4];

    const int tid = threadIdx.x;
    const int lane = tid & 63;
    const int w = tid >> 6;
    const int hl = lane >> 4;
    const int l15 = lane & 15;
    const int b = blockIdx.x;

    // ---- fused per-qubit gate matrices (threads 0..71) ----
    if (tid < 72) {
        const int l = tid / NQ;
        const int q = tid % NQ;
        const float* pp = wgt + (l < NLAYERS ? l * (3 * NQ) : NLAYERS * (3 * NQ)) + q * 3;
        float s0, c0, s1, c1, s2, c2;
        sincosf(0.5f * pp[0], &s0, &c0);
        sincosf(0.5f * pp[1], &s1, &c1);
        sincosf(0.5f * pp[2], &s2, &c2);
        float2 U[4], M[4];
        if (l < NLAYERS) {
            float2 RX[4] = { {c0, 0.f}, {0.f, -s0}, {0.f, -s0}, {c0, 0.f} };
            float2 RY[4] = { {c1, 0.f}, {-s1, 0.f}, {s1, 0.f}, {c1, 0.f} };
            float2 RZ[4] = { {c2, -s2}, {0.f, 0.f}, {0.f, 0.f}, {c2, s2} };
            mat2mul(RY, RX, M);
            mat2mul(RZ, M, U);
        } else {
            float2 RY0[4] = { {c0, 0.f}, {-s0, 0.f}, {s0, 0.f}, {c0, 0.f} };
            float2 RZ1[4] = { {c1, -s1}, {0.f, 0.f}, {0.f, 0.f}, {c1, s1} };
            float2 RY2[4] = { {c2, 0.f}, {-s2, 0.f}, {s2, 0.f}, {c2, 0.f} };
            mat2mul(RZ1, RY0, M);
            mat2mul(RY2, M, U);
        }
        gmat[tid * 4 + 0] = U[0];
        gmat[tid * 4 + 1] = U[1];
        gmat[tid * 4 + 2] = U[2];
        gmat[tid * 4 + 3] = U[3];
    }

    // ---- load x (i = 16*tid + j), sum of squares ----
    const float* xb = x + (size_t)b * 4096;
    float vals[16];
    float ss = 0.f;
    {
        const float4* xv = reinterpret_cast<const float4*>(xb + 16 * tid);
        #pragma unroll
        for (int k = 0; k < 4; ++k) {
            float4 v = xv[k];
            vals[k * 4 + 0] = v.x; vals[k * 4 + 1] = v.y;
            vals[k * 4 + 2] = v.z; vals[k * 4 + 3] = v.w;
            ss += v.x * v.x + v.y * v.y + v.z * v.z + v.w * v.w;
        }
    }
    #pragma unroll
    for (int off = 32; off > 0; off >>= 1) ss += __shfl_down(ss, off, 64);
    if (lane == 0) red[w] = ss;
    __syncthreads();   // gmat + red visible

    const float total = red[0] + red[1] + red[2] + red[3];
    const float inv = 1.0f / sqrtf(sqrtf(total) + 1e-12f);

    // ---- initial state into buf 0 (kappa = i, v = tid, m = j): 4x b128 ----
    const int vkT = tid ^ (((tid >> 3) ^ (tid >> 7)) & 1);
    #pragma unroll
    for (int jq = 0; jq < 4; ++jq) {
        const int base = (vkT << 4) | (((jq ^ tid) & 3) << 2);
        uint4 eq;
        eq.x = cvt2(vals[jq * 4 + 0] * inv, 0.f);
        eq.y = cvt2(vals[jq * 4 + 1] * inv, 0.f);
        eq.z = cvt2(vals[jq * 4 + 2] * inv, 0.f);
        eq.w = cvt2(vals[jq * 4 + 3] * inv, 0.f);
        *reinterpret_cast<uint4*>(&st[0][base]) = eq;
    }

    // ---- W for phase 0 (layer 0, beta 0) into plane 0 ----
    {
        unsigned wrd, wid;
        buildW(gmat, 0, 0, tid, wrd, wid);
        wrp[0][tid] = wrd; wip[0][tid] = wid;
    }

    // ---- per-thread address constants ----
    const int v0 = (w << 6) | l15;
    const int vk0 = v0 ^ ((((v0 >> 3) ^ (v0 >> 7)) & 1));
    const int rbase = (vk0 << 4) | ((hl ^ (l15 & 3)) << 2);
    const int af = l15 * 16 + 4 * hl;
    int bw[4], pg[4], pt[4];
    const int sgb = slotOf((4 * hl) << 8);
    const int plc = slotOf(permL(l15));
    #pragma unroll
    for (int ti = 0; ti < 4; ++ti) {
        bw[ti] = sgb ^ slotOf((((4 * w + ti) << 4) | l15));
        pt[ti] = plc ^ slotOf(permT(4 * w + ti));
    }
    #pragma unroll
    for (int g = 0; g < 4; ++g) pg[g] = slotOf(permR(4 * hl + g));
    const int obase = ((4 * hl) << 8) | ((4 * w) << 4) | l15;
    float* outp = out + (size_t)b * 4096;

    __syncthreads();   // buf0 + plane0 visible

    const v4f z = {0.f, 0.f, 0.f, 0.f};

    // ---- phases 0..16 (phase 17 peeled as epilogue) ----
    #pragma unroll 1
    for (int p = 0; p < 17; ++p) {
        const unsigned* __restrict__ stR = &st[p & 1][0];
        unsigned* __restrict__ stW = &st[(p + 1) & 1][0];

        v8s a_crh, a_crl, a_cih, a_cil;
        makeAfrags(&wrp[p & 1][0], &wip[p & 1][0], af, a_crh, a_crl, a_cih, a_cil);

        const uint4 s0 = *reinterpret_cast<const uint4*>(stR + rbase);
        const uint4 s1 = *reinterpret_cast<const uint4*>(stR + rbase + 256);
        const uint4 s2 = *reinterpret_cast<const uint4*>(stR + rbase + 512);
        const uint4 s3 = *reinterpret_cast<const uint4*>(stR + rbase + 768);

        unsigned ent[4][4];
        #pragma unroll
        for (int ti = 0; ti < 4; ++ti) {
            const uint4 sv = (ti == 0) ? s0 : (ti == 1) ? s1 : (ti == 2) ? s2 : s3;
            const v8s bsv = pk4(sv.x, sv.y, sv.z, sv.w);
            v4f cr = MFMA(a_crl, bsv, z);
            cr = MFMA(a_crh, bsv, cr);
            v4f ci = MFMA(a_cil, bsv, z);
            ci = MFMA(a_cih, bsv, ci);
            #pragma unroll
            for (int g = 0; g < 4; ++g)
                ent[ti][g] = cvt2(cr[g], ci[g]);
        }

        // W for phase p+1 into the other plane (no reader conflict: plane
        // (p+1)&1 was last read in phase p-1, before the last barrier)
        {
            const int pn = p + 1;
            unsigned wrd, wid;
            buildW(gmat, pn / 3, 4 * (pn % 3), tid, wrd, wid);
            wrp[pn & 1][tid] = wrd;
            wip[pn & 1][tid] = wid;
        }

        // state writes into the other buffer (same safety argument)
        if (p % 3 == 2) {
            // layer end: CNOT-ring perm fused into the write
            #pragma unroll
            for (int ti = 0; ti < 4; ++ti) {
                #pragma unroll
                for (int g = 0; g < 4; ++g)
                    stW[pg[g] ^ pt[ti]] = ent[ti][g];
            }
        } else {
            #pragma unroll
            for (int ti = 0; ti < 4; ++ti) {
                #pragma unroll
                for (int g = 0; g < 4; ++g)
                    stW[bw[ti] + (g << 8)] = ent[ti][g];
            }
        }
        __syncthreads();   // the ONE barrier per phase
    }

    // ---- phase 17 (layer 5, beta 8): real part straight to global ----
    {
        const unsigned* __restrict__ stR = &st[1][0];
        v8s a_crh, a_crl, a_cih, a_cil;
        makeAfrags(&wrp[1][0], &wip[1][0], af, a_crh, a_crl, a_cih, a_cil);
        #pragma unroll
        for (int ti = 0; ti < 4; ++ti) {
            const uint4 sv = *reinterpret_cast<const uint4*>(stR + rbase + ti * 256);
            const v8s bsv = pk4(sv.x, sv.y, sv.z, sv.w);
            v4f cr = MFMA(a_crl, bsv, z);
            cr = MFMA(a_crh, bsv, cr);
            #pragma unroll
            for (int g = 0; g < 4; ++g)
                outp[obase + (g << 8) + (ti << 4)] = cr[g];
        }
    }
}

extern "C" void kernel_launch(void* const* d_in, const int* in_sizes, int n_in,
                              void* d_out, int out_size, void* d_ws, size_t ws_size,
                              hipStream_t stream) {
    const float* x = (const float*)d_in[0];      // [1024, 4096] f32
    const float* wgt = (const float*)d_in[1];    // [216] f32
    float* out = (float*)d_out;                  // [1024, 4096] f32
    qsim_kernel<<<dim3(1024), dim3(TPB), 0, stream>>>(x, wgt, out);
}

// Round 12
// 35.161 us; speedup vs baseline: 1.0188x; 1.0188x over previous
//
#include <hip/hip_runtime.h>
#include <math.h>

#define NQ 12
#define NLAYERS 5
#define TPB 256

typedef float v4f __attribute__((ext_vector_type(4)));
typedef short v8s __attribute__((ext_vector_type(8)));

#define MFMA(A, B, C) __builtin_amdgcn_mfma_f32_16x16x32_bf16((A), (B), (C), 0, 0, 0)

// ---- complex helpers (gate/W build, pre-kernel only) ----
__device__ __forceinline__ float2 cmulf(float2 a, float2 b) {
    return make_float2(a.x * b.x - a.y * b.y, a.x * b.y + a.y * b.x);
}
__device__ __forceinline__ float2 caddf(float2 a, float2 b) {
    return make_float2(a.x + b.x, a.y + b.y);
}
__device__ __forceinline__ void mat2mul(const float2 A[4], const float2 B[4], float2 C[4]) {
    C[0] = caddf(cmulf(A[0], B[0]), cmulf(A[1], B[2]));
    C[1] = caddf(cmulf(A[0], B[1]), cmulf(A[1], B[3]));
    C[2] = caddf(cmulf(A[2], B[0]), cmulf(A[3], B[2]));
    C[3] = caddf(cmulf(A[2], B[1]), cmulf(A[3], B[3]));
}

__device__ __forceinline__ v8s pk4(unsigned a, unsigned b, unsigned c, unsigned d) {
    union { unsigned u[4]; v8s s; } x;
    x.u[0] = a; x.u[1] = b; x.u[2] = c; x.u[3] = d;
    return x.s;
}
__device__ __forceinline__ unsigned cvt2(float a, float b) {   // {bf16(a) lo16, bf16(b) hi16}
    unsigned d;
    asm("v_cvt_pk_bf16_f32 %0, %1, %2" : "=v"(d) : "v"(a), "v"(b));
    return d;
}
// f32 -> {bf16rne(f) lo16, bf16(f - hi) hi16}  (split-W: hi+lo ~ 18-bit exact)
__device__ __forceinline__ unsigned packhl_rne(float f) {
    unsigned h = cvt2(f, 0.0f);
    float lo = f - __uint_as_float(h << 16);
    unsigned l = cvt2(lo, 0.0f);
    return h | (l << 16);
}

// ---- ring-of-CNOT permutation p = y^{-1} (HW-verified R8-R11) ----
__device__ __forceinline__ int sx4(int x) { x ^= x >> 1; x ^= x >> 2; return x & 15; }
__device__ __forceinline__ int permR(int row) {
    int s = sx4(row), par = s & 1;
    return ((s ^ (par << 3)) << 8) | (par ? 0xFF : 0);
}
__device__ __forceinline__ int permT(int t) {
    int s = sx4(t), par = s & 1;
    return (par << 11) | (s << 4) | (par ? 0xF : 0);
}
__device__ __forceinline__ int permL(int lo) {
    int s = sx4(lo), par = s & 1;
    return s | (par << 11);
}

// ---- GF(2)-linear slot keying (HW-verified R9-R11) ----
__device__ __forceinline__ int slotOf(int k) {
    int v = k >> 4, m = k & 15;
    int vk = v ^ (((v >> 3) ^ (v >> 7)) & 1);
    return (vk << 4) | ((((m >> 2) ^ v) & 3) << 2) | (m & 3);
}

// W = Kron of 4 gates (qubits 11-beta-0..3); thread -> entry (r=tid>>4, c=tid&15)
__device__ __forceinline__ void buildW(const float2* gm, int layer, int beta, int tid,
                                       unsigned& wrd, unsigned& wid) {
    const int r = tid >> 4, c = tid & 15;
    float2 u = make_float2(1.f, 0.f);
    #pragma unroll
    for (int bb = 0; bb < 4; ++bb) {
        const float2 e = gm[(layer * 12 + 11 - beta - bb) * 4 + ((r >> bb) & 1) * 2 + ((c >> bb) & 1)];
        u = cmulf(u, e);
    }
    wrd = packhl_rne(u.x);
    wid = packhl_rne(u.y);
}

// Build the 4 split-bf16 A-fragments {Wr,-Wi}h/l, {Wi,Wr}h/l from register W rows.
__device__ __forceinline__ void makeAfrags(uint4 wr4, uint4 wi4,
                                           v8s& a_crh, v8s& a_crl, v8s& a_cih, v8s& a_cil) {
    const unsigned NX = 0x80008000u;
    const unsigned SLO = 0x05040100u, SHI = 0x07060302u;
    unsigned n0 = wi4.x ^ NX, n1 = wi4.y ^ NX, n2 = wi4.z ^ NX, n3 = wi4.w ^ NX;
    a_crh = pk4(__builtin_amdgcn_perm(n0, wr4.x, SLO), __builtin_amdgcn_perm(n1, wr4.y, SLO),
                __builtin_amdgcn_perm(n2, wr4.z, SLO), __builtin_amdgcn_perm(n3, wr4.w, SLO));
    a_crl = pk4(__builtin_amdgcn_perm(n0, wr4.x, SHI), __builtin_amdgcn_perm(n1, wr4.y, SHI),
                __builtin_amdgcn_perm(n2, wr4.z, SHI), __builtin_amdgcn_perm(n3, wr4.w, SHI));
    a_cih = pk4(__builtin_amdgcn_perm(wr4.x, wi4.x, SLO), __builtin_amdgcn_perm(wr4.y, wi4.y, SLO),
                __builtin_amdgcn_perm(wr4.z, wi4.z, SLO), __builtin_amdgcn_perm(wr4.w, wi4.w, SLO));
    a_cil = pk4(__builtin_amdgcn_perm(wr4.x, wi4.x, SHI), __builtin_amdgcn_perm(wr4.y, wi4.y, SHI),
                __builtin_amdgcn_perm(wr4.z, wi4.z, SHI), __builtin_amdgcn_perm(wr4.w, wi4.w, SHI));
}

// ---- pre-kernel: compute all 18 W planes once, into d_ws ----
// layout: ws[0*4608 + p*256 + tid] = W-real {hi,lo}; ws[4608 + p*256 + tid] = W-imag
__global__ __launch_bounds__(TPB) void wprep_kernel(const float* __restrict__ wgt,
                                                    unsigned* __restrict__ ws) {
    __shared__ float2 gmat[288];
    const int tid = threadIdx.x;
    if (tid < 72) {
        const int l = tid / NQ;
        const int q = tid % NQ;
        const float* pp = wgt + (l < NLAYERS ? l * (3 * NQ) : NLAYERS * (3 * NQ)) + q * 3;
        float s0, c0, s1, c1, s2, c2;
        sincosf(0.5f * pp[0], &s0, &c0);
        sincosf(0.5f * pp[1], &s1, &c1);
        sincosf(0.5f * pp[2], &s2, &c2);
        float2 U[4], M[4];
        if (l < NLAYERS) {
            float2 RX[4] = { {c0, 0.f}, {0.f, -s0}, {0.f, -s0}, {c0, 0.f} };
            float2 RY[4] = { {c1, 0.f}, {-s1, 0.f}, {s1, 0.f}, {c1, 0.f} };
            float2 RZ[4] = { {c2, -s2}, {0.f, 0.f}, {0.f, 0.f}, {c2, s2} };
            mat2mul(RY, RX, M);
            mat2mul(RZ, M, U);
        } else {
            float2 RY0[4] = { {c0, 0.f}, {-s0, 0.f}, {s0, 0.f}, {c0, 0.f} };
            float2 RZ1[4] = { {c1, -s1}, {0.f, 0.f}, {0.f, 0.f}, {c1, s1} };
            float2 RY2[4] = { {c2, 0.f}, {-s2, 0.f}, {s2, 0.f}, {c2, 0.f} };
            mat2mul(RZ1, RY0, M);
            mat2mul(RY2, M, U);
        }
        gmat[tid * 4 + 0] = U[0];
        gmat[tid * 4 + 1] = U[1];
        gmat[tid * 4 + 2] = U[2];
        gmat[tid * 4 + 3] = U[3];
    }
    __syncthreads();
    #pragma unroll 1
    for (int p = 0; p < 18; ++p) {
        unsigned wrd, wid;
        buildW(gmat, p / 3, 4 * (p % 3), tid, wrd, wid);
        ws[p * 256 + tid] = wrd;
        ws[18 * 256 + p * 256 + tid] = wid;
    }
}

__global__ __launch_bounds__(TPB) void qsim_kernel(const float* __restrict__ x,
                                                   const unsigned* __restrict__ ws,
                                                   float* __restrict__ out) {
    // Double-buffered state only; W comes from global (L2-broadcast), prefetched.
    __shared__ __align__(16) unsigned st[2][4096];   // 32 KB
    __shared__ float red[4];

    const int tid = threadIdx.x;
    const int lane = tid & 63;
    const int w = tid >> 6;
    const int hl = lane >> 4;
    const int l15 = lane & 15;
    const int b = blockIdx.x;

    // ---- load x (i = 16*tid + j), sum of squares ----
    const float* xb = x + (size_t)b * 4096;
    float vals[16];
    float ss = 0.f;
    {
        const float4* xv = reinterpret_cast<const float4*>(xb + 16 * tid);
        #pragma unroll
        for (int k = 0; k < 4; ++k) {
            float4 v = xv[k];
            vals[k * 4 + 0] = v.x; vals[k * 4 + 1] = v.y;
            vals[k * 4 + 2] = v.z; vals[k * 4 + 3] = v.w;
            ss += v.x * v.x + v.y * v.y + v.z * v.z + v.w * v.w;
        }
    }
    #pragma unroll
    for (int off = 32; off > 0; off >>= 1) ss += __shfl_down(ss, off, 64);
    if (lane == 0) red[w] = ss;
    __syncthreads();

    const float total = red[0] + red[1] + red[2] + red[3];
    const float inv = 1.0f / sqrtf(sqrtf(total) + 1e-12f);

    // ---- initial state into buf 0 (kappa = i, v = tid, m = j): 4x b128 ----
    const int vkT = tid ^ (((tid >> 3) ^ (tid >> 7)) & 1);
    #pragma unroll
    for (int jq = 0; jq < 4; ++jq) {
        const int base = (vkT << 4) | (((jq ^ tid) & 3) << 2);
        uint4 eq;
        eq.x = cvt2(vals[jq * 4 + 0] * inv, 0.f);
        eq.y = cvt2(vals[jq * 4 + 1] * inv, 0.f);
        eq.z = cvt2(vals[jq * 4 + 2] * inv, 0.f);
        eq.w = cvt2(vals[jq * 4 + 3] * inv, 0.f);
        *reinterpret_cast<uint4*>(&st[0][base]) = eq;
    }

    // ---- per-thread address constants (HW-verified R9-R11) ----
    const int v0 = (w << 6) | l15;
    const int vk0 = v0 ^ ((((v0 >> 3) ^ (v0 >> 7)) & 1));
    const int rbase = (vk0 << 4) | ((hl ^ (l15 & 3)) << 2);
    const int af = l15 * 16 + 4 * hl;
    int bw[4], pg[4], pt[4];
    const int sgb = slotOf((4 * hl) << 8);
    const int plc = slotOf(permL(l15));
    #pragma unroll
    for (int ti = 0; ti < 4; ++ti) {
        bw[ti] = sgb ^ slotOf((((4 * w + ti) << 4) | l15));
        pt[ti] = plc ^ slotOf(permT(4 * w + ti));
    }
    #pragma unroll
    for (int g = 0; g < 4; ++g) pg[g] = slotOf(permR(4 * hl + g));
    const int obase = ((4 * hl) << 8) | ((4 * w) << 4) | l15;
    float* outp = out + (size_t)b * 4096;

    const unsigned* gWr = ws;
    const unsigned* gWi = ws + 18 * 256;

    // W for phase 0 (L2-resident after first block touches it)
    uint4 wrC = *reinterpret_cast<const uint4*>(gWr + af);
    uint4 wiC = *reinterpret_cast<const uint4*>(gWi + af);

    __syncthreads();   // buf0 visible

    const v4f z = {0.f, 0.f, 0.f, 0.f};

    // ---- phases 0..16 (phase 17 peeled as epilogue) ----
    #pragma unroll 1
    for (int p = 0; p < 17; ++p) {
        const unsigned* __restrict__ stR = &st[p & 1][0];
        unsigned* __restrict__ stW = &st[(p + 1) & 1][0];

        // state reads (issue first)
        const uint4 s0 = *reinterpret_cast<const uint4*>(stR + rbase);
        const uint4 s1 = *reinterpret_cast<const uint4*>(stR + rbase + 256);
        const uint4 s2 = *reinterpret_cast<const uint4*>(stR + rbase + 512);
        const uint4 s3 = *reinterpret_cast<const uint4*>(stR + rbase + 768);

        // prefetch next phase's W (L2 hit; latency hides under MFMAs)
        const uint4 wrN = *reinterpret_cast<const uint4*>(gWr + (p + 1) * 256 + af);
        const uint4 wiN = *reinterpret_cast<const uint4*>(gWi + (p + 1) * 256 + af);

        v8s a_crh, a_crl, a_cih, a_cil;
        makeAfrags(wrC, wiC, a_crh, a_crl, a_cih, a_cil);

        unsigned ent[4][4];
        #pragma unroll
        for (int ti = 0; ti < 4; ++ti) {
            const uint4 sv = (ti == 0) ? s0 : (ti == 1) ? s1 : (ti == 2) ? s2 : s3;
            const v8s bsv = pk4(sv.x, sv.y, sv.z, sv.w);
            v4f cr = MFMA(a_crl, bsv, z);
            cr = MFMA(a_crh, bsv, cr);
            v4f ci = MFMA(a_cil, bsv, z);
            ci = MFMA(a_cih, bsv, ci);
            #pragma unroll
            for (int g = 0; g < 4; ++g)
                ent[ti][g] = cvt2(cr[g], ci[g]);
        }

        // write into the other buffer (read in p-1, drained by p-1's barrier)
        if (p % 3 == 2) {
            // layer end: CNOT-ring perm fused into the write
            #pragma unroll
            for (int ti = 0; ti < 4; ++ti) {
                #pragma unroll
                for (int g = 0; g < 4; ++g)
                    stW[pg[g] ^ pt[ti]] = ent[ti][g];
            }
        } else {
            #pragma unroll
            for (int ti = 0; ti < 4; ++ti) {
                #pragma unroll
                for (int g = 0; g < 4; ++g)
                    stW[bw[ti] + (g << 8)] = ent[ti][g];
            }
        }
        __syncthreads();   // one barrier per phase

        wrC = wrN; wiC = wiN;
    }

    // ---- phase 17 (layer 5, beta 8): real part straight to global ----
    {
        const unsigned* __restrict__ stR = &st[1][0];
        v8s a_crh, a_crl, a_cih, a_cil;
        makeAfrags(wrC, wiC, a_crh, a_crl, a_cih, a_cil);
        #pragma unroll
        for (int ti = 0; ti < 4; ++ti) {
            const uint4 sv = *reinterpret_cast<const uint4*>(stR + rbase + ti * 256);
            const v8s bsv = pk4(sv.x, sv.y, sv.z, sv.w);
            v4f cr = MFMA(a_crl, bsv, z);
            cr = MFMA(a_crh, bsv, cr);
            #pragma unroll
            for (int g = 0; g < 4; ++g)
                outp[obase + (g << 8) + (ti << 4)] = cr[g];
        }
    }
}

extern "C" void kernel_launch(void* const* d_in, const int* in_sizes, int n_in,
                              void* d_out, int out_size, void* d_ws, size_t ws_size,
                              hipStream_t stream) {
    const float* x = (const float*)d_in[0];      // [1024, 4096] f32
    const float* wgt = (const float*)d_in[1];    // [216] f32
    float* out = (float*)d_out;                  // [1024, 4096] f32
    unsigned* ws = (unsigned*)d_ws;              // 2 x 18 x 256 dwords = 36 KB
    wprep_kernel<<<dim3(1), dim3(TPB), 0, stream>>>(wgt, ws);
    qsim_kernel<<<dim3(1024), dim3(TPB), 0, stream>>>(x, ws, out);
}